// Round 5
// baseline (484.443 us; speedup 1.0000x reference)
//
#include <hip/hip_runtime.h>
#include <hip/hip_bf16.h>
#include <stdint.h>

#define S_LEN 2048
#define NB 2
#define NH 16
#define HDIM 128
#define RDIM 64
#define DF 192          // HDIM + RDIM
#define MROWS 4096      // NB * S_LEN

typedef __bf16 bf16_t;
typedef __attribute__((ext_vector_type(8))) __bf16 bf16x8;
typedef __attribute__((ext_vector_type(4))) __bf16 bf16x4;
typedef __attribute__((ext_vector_type(4))) float f32x4;
typedef __attribute__((ext_vector_type(4))) float float4v;

__device__ __forceinline__ void gload_lds16(const bf16_t* g, bf16_t* l) {
  __builtin_amdgcn_global_load_lds(
      (const __attribute__((address_space(1))) void*)g,
      (__attribute__((address_space(3))) void*)l, 16, 0, 0);
}

// ---------------- convert f32 -> bf16 (contiguous) ----------------
__global__ __launch_bounds__(256) void convert_bf16(const float* __restrict__ in,
                                                    bf16_t* __restrict__ out, int n4) {
  int i = blockIdx.x * 256 + threadIdx.x;
  if (i >= n4) return;
  float4v v = *reinterpret_cast<const float4v*>(&in[(size_t)i * 4]);
  bf16x4 o;
  o[0] = (bf16_t)v[0]; o[1] = (bf16_t)v[1]; o[2] = (bf16_t)v[2]; o[3] = (bf16_t)v[3];
  *reinterpret_cast<bf16x4*>(&out[(size_t)i * 4]) = o;
}

// ---------------- transpose (K,N) f32 -> (N,K) bf16 ----------------
__global__ __launch_bounds__(256) void transpose_bf16(const float* __restrict__ in,
                                                      bf16_t* __restrict__ out,
                                                      int K, int N) {
  __shared__ float t[64][65];
  const int n0 = blockIdx.x * 64, k0 = blockIdx.y * 64;
  const int tx = threadIdx.x & 63, ty = threadIdx.x >> 6;
#pragma unroll
  for (int i = ty; i < 64; i += 4)
    t[i][tx] = in[(size_t)(k0 + i) * N + n0 + tx];
  __syncthreads();
#pragma unroll
  for (int i = ty; i < 64; i += 4)
    out[(size_t)(n0 + i) * K + k0 + tx] = (bf16_t)t[tx][i];
}

// ---------------- GEMM: C(M,N) = A(M,K) * Bt(N,K)^T ----------------
// MODE 1: f32 out + bias (final projection)
// MODE 5: fused xb@[Wlq|Wkv|Wkr]: col<1536 -> cq ; col<2048 -> ckv ; else kr rope->kf
// MODE 6: fused cq@[Wq|Wqr]:      col<2048 -> qf d<128 ; else qr rope->qf
// MODE 7: fused ckv@[Wk|Wv]:      col<2048 -> kf d<128 ; else v -> vT
struct EpiParams {
  bf16_t* o0;
  bf16_t* o1;
  bf16_t* o2;
  float* outf;
  const float* bias;
  const float* cosb;
  const float* sinb;
};

template <int MODE>
__global__ __launch_bounds__(256) void gemm_bt(const bf16_t* __restrict__ A,
                                               const bf16_t* __restrict__ Bt,
                                               int M, int N, int K, EpiParams ep) {
  const int tid = threadIdx.x;
  const int lane = tid & 63, w = tid >> 6;
  const int l15 = lane & 15, lg = lane >> 4;
  const int m0 = blockIdx.y * 128, n0 = blockIdx.x * 128;
  const int mw = (w >> 1) * 64, nw = (w & 1) * 64;
  __shared__ alignas(16) bf16_t As[128 * 32];
  __shared__ alignas(16) bf16_t Bs[128 * 32];

  f32x4 acc[4][4] = {};
  const int row_ld = tid >> 2;            // 0..63
  const int col8 = (tid & 3) * 8;
  const bf16_t* ag = A + (size_t)(m0 + row_ld) * K + col8;
  const bf16_t* bg = Bt + (size_t)(n0 + row_ld) * K + col8;
  const unsigned wbase = (unsigned)(tid & ~63u) * 8;  // elems

  for (int k0 = 0; k0 < K; k0 += 32) {
    __syncthreads();
    gload_lds16(ag + k0, As + wbase);
    gload_lds16(ag + (size_t)64 * K + k0, As + 2048 + wbase);
    gload_lds16(bg + k0, Bs + wbase);
    gload_lds16(bg + (size_t)64 * K + k0, Bs + 2048 + wbase);
    __syncthreads();
    bf16x8 a[4], b[4];
#pragma unroll
    for (int i = 0; i < 4; ++i)
      a[i] = *reinterpret_cast<const bf16x8*>(&As[(mw + i * 16 + l15) * 32 + lg * 8]);
#pragma unroll
    for (int i = 0; i < 4; ++i)
      b[i] = *reinterpret_cast<const bf16x8*>(&Bs[(nw + i * 16 + l15) * 32 + lg * 8]);
#pragma unroll
    for (int i = 0; i < 4; ++i)
#pragma unroll
      for (int j = 0; j < 4; ++j)
        acc[i][j] = __builtin_amdgcn_mfma_f32_16x16x32_bf16(a[i], b[j], acc[i][j], 0, 0, 0);
  }

#pragma unroll
  for (int i = 0; i < 4; ++i)
#pragma unroll
    for (int j = 0; j < 4; ++j) {
      const int col = n0 + nw + j * 16 + l15;
#pragma unroll
      for (int r = 0; r < 4; ++r) {
        const int row = m0 + mw + i * 16 + lg * 4 + r;
        float v = acc[i][j][r];
        const int b = row >> 11, s = row & 2047;
        if constexpr (MODE == 1) {
          ep.outf[(size_t)row * N + col] = v + ep.bias[col];
        } else if constexpr (MODE == 5) {
          if (col < 1536) {
            ep.o0[(size_t)row * 1536 + col] = (bf16_t)v;
          } else if (col < 2048) {
            ep.o1[(size_t)row * 512 + (col - 1536)] = (bf16_t)v;
          } else {
            const int c2 = col - 2048;
            float vb = v + ep.bias[c2];
            float other = __shfl_xor(vb, 1, 64);
            const int h = c2 >> 6, dr = c2 & 63;
            const int fi = dr >> 1;
            const float c = ep.cosb[s * 32 + fi];
            const float sn = ep.sinb[s * 32 + fi];
            const float o = (c2 & 1) ? (other * sn + vb * c) : (vb * c - other * sn);
            ep.o2[(((size_t)(b * NH + h)) * S_LEN + s) * DF + 128 + dr] = (bf16_t)o;
          }
        } else if constexpr (MODE == 6) {
          if (col < 2048) {
            const int h = col >> 7, d = col & 127;
            ep.o0[(((size_t)(b * NH + h)) * S_LEN + s) * DF + d] = (bf16_t)v;
          } else {
            const int c2 = col - 2048;
            float vb = v + ep.bias[c2];
            float other = __shfl_xor(vb, 1, 64);
            const int h = c2 >> 6, dr = c2 & 63;
            const int fi = dr >> 1;
            const float c = ep.cosb[s * 32 + fi];
            const float sn = ep.sinb[s * 32 + fi];
            const float o = (c2 & 1) ? (other * sn + vb * c) : (vb * c - other * sn);
            ep.o0[(((size_t)(b * NH + h)) * S_LEN + s) * DF + 128 + dr] = (bf16_t)o;
          }
        } else {  // MODE 7
          if (col < 2048) {
            const int h = col >> 7, d = col & 127;
            ep.o0[(((size_t)(b * NH + h)) * S_LEN + s) * DF + d] = (bf16_t)v;
          } else {
            const int c2 = col - 2048;
            const int h = c2 >> 7, d = c2 & 127;
            ep.o1[(((size_t)(b * NH + h)) * HDIM + d) * S_LEN + s] = (bf16_t)v;
          }
        }
      }
    }
}

// ---------------- flash attention (causal), pipelined staging ----------------
// qf,kf: (B,H,S,192) bf16 ; vT: (B,H,128,S) bf16 ; att: (B,S,H*128) bf16
// Block: 8 waves x 16 q-rows = 128 q rows. KV tile = 64 keys.
// K double-buffered, V single-buffered. Raw s_barrier + counted vmcnt so
// prefetched loads stay in flight across barriers (T3/T4). XCD-grouped
// block swizzle: 4 heads per XCD -> K/V L2-resident (T1).
__global__ __launch_bounds__(512, 4) void attn_fwd(const bf16_t* __restrict__ qf,
                                                   const bf16_t* __restrict__ kf,
                                                   const bf16_t* __restrict__ vT,
                                                   bf16_t* __restrict__ att) {
  const int tid = threadIdx.x;
  const int lane = tid & 63, w = tid >> 6;   // w: 0..7
  const int l15 = lane & 15, lg = lane >> 4;
  // XCD-grouped swizzle: block l -> XCD l%8; 4 bh per XCD, heavy q first.
  const int l = blockIdx.x;                  // 0..511
  const int bh = (l & 7) * 4 + ((l >> 3) & 3);
  const int qchunk = l >> 5;                 // 0..15
  const int qb0 = (15 - qchunk) * 128;
  const int q0 = qb0 + w * 16;
  const float scale = 0.07216878364870322f;  // 1/sqrt(192)

  __shared__ alignas(16) bf16_t Ks[2 * 64 * 192];  // 48 KB, double-buffered
  __shared__ alignas(16) bf16_t Vs[128 * 64];      // 16 KB
  __shared__ alignas(16) bf16_t Ps[8 * 16 * 64];   // 16 KB, XOR-swizzled
  // total exactly 80 KB -> 2 blocks/CU

  // Q fragments held for the whole loop
  const bf16_t* qptr = qf + ((size_t)bh * S_LEN + q0 + l15) * DF + lg * 8;
  bf16x8 qfr[6];
#pragma unroll
  for (int d = 0; d < 6; ++d) qfr[d] = *reinterpret_cast<const bf16x8*>(qptr + d * 32);

  f32x4 o[8] = {};
  float m[4], lsum[4];
#pragma unroll
  for (int r = 0; r < 4; ++r) { m[r] = -1e30f; lsum[r] = 0.0f; }

  const bf16_t* kb0 = kf + (size_t)bh * S_LEN * DF;
  const bf16_t* vb0 = vT + (size_t)bh * HDIM * S_LEN;
  const int njt = qb0 / 64 + 2;
  const int wslot = tid & ~63;

  auto stage_K = [&](int jtile, int buf) {
    const bf16_t* kTile = kb0 + (size_t)jtile * 64 * DF;
    bf16_t* dst = Ks + buf * (64 * 192);
#pragma unroll
    for (int i = 0; i < 3; ++i) {
      const int s = i * 512 + tid;
      const int row = s / 24;
      const int c = s - row * 24;
      const int cs = c ^ (row & 7);
      gload_lds16(kTile + (size_t)row * DF + cs * 8, dst + (size_t)(i * 512 + wslot) * 8);
    }
  };
  auto stage_V = [&](int jtile) {
    const bf16_t* vTile = vb0 + jtile * 64;
#pragma unroll
    for (int i = 0; i < 2; ++i) {
      const int s = i * 512 + tid;
      const int row = s >> 3;
      const int c = s & 7;
      const int cs = c ^ (row & 7);
      gload_lds16(vTile + (size_t)row * S_LEN + cs * 8, Vs + (size_t)(i * 512 + wslot) * 8);
    }
  };

  stage_K(0, 0);  // prologue: K[0] -> buf 0

  for (int jt = 0; jt < njt; ++jt) {
    const int j0 = jt * 64;
    const int cur = jt & 1;
    // B1: everyone done with previous iteration's compute (V + Ks[cur^1] reads)
    __builtin_amdgcn_s_barrier();
    __builtin_amdgcn_sched_barrier(0);
    stage_V(jt);                                   // 2 loads (oldest)
    const int jn = (jt + 1 < njt) ? jt + 1 : jt;   // clamped prefetch
    stage_K(jn, cur ^ 1);                          // 3 loads
    // wait: K[jt] (issued last iter) landed; leave this iter's 5 in flight
    asm volatile("s_waitcnt vmcnt(5)" ::: "memory");
    __builtin_amdgcn_s_barrier();
    __builtin_amdgcn_sched_barrier(0);

    const bool active = (j0 <= q0 + 15);
    float sv[16];
    if (active) {
      const bf16_t* kbuf = Ks + cur * (64 * 192);
      f32x4 sa[4] = {};
      __builtin_amdgcn_s_setprio(1);
#pragma unroll
      for (int jf = 0; jf < 4; ++jf) {
        const int krow = jf * 16 + l15;
        const int ksw = krow & 7;
#pragma unroll
        for (int d = 0; d < 6; ++d) {
          const int kc = (4 * d + lg) ^ ksw;
          bf16x8 kfr = *reinterpret_cast<const bf16x8*>(&kbuf[krow * 192 + kc * 8]);
          sa[jf] = __builtin_amdgcn_mfma_f32_16x16x32_bf16(qfr[d], kfr, sa[jf], 0, 0, 0);
        }
      }
      __builtin_amdgcn_s_setprio(0);

      const bool full = (j0 + 63 <= q0);
#pragma unroll
      for (int jf = 0; jf < 4; ++jf)
#pragma unroll
        for (int r = 0; r < 4; ++r) {
          float x = sa[jf][r] * scale;
          if (!full) {
            const int j = j0 + jf * 16 + l15;
            const int qi = q0 + lg * 4 + r;
            if (j > qi) x = -1e30f;
          }
          sv[jf * 4 + r] = x;
        }

      float tmax[4];
#pragma unroll
      for (int r = 0; r < 4; ++r)
        tmax[r] = fmaxf(fmaxf(sv[r], sv[4 + r]), fmaxf(sv[8 + r], sv[12 + r]));
#pragma unroll
      for (int xm = 1; xm < 16; xm <<= 1)
#pragma unroll
        for (int r = 0; r < 4; ++r) tmax[r] = fmaxf(tmax[r], __shfl_xor(tmax[r], xm, 64));
      float alpha[4];
#pragma unroll
      for (int r = 0; r < 4; ++r) {
        const float mn = fmaxf(m[r], tmax[r]);
        alpha[r] = __expf(m[r] - mn);
        m[r] = mn;
      }
#pragma unroll
      for (int jf = 0; jf < 4; ++jf)
#pragma unroll
        for (int r = 0; r < 4; ++r) sv[jf * 4 + r] = __expf(sv[jf * 4 + r] - m[r]);
      float rs[4];
#pragma unroll
      for (int r = 0; r < 4; ++r)
        rs[r] = (sv[r] + sv[4 + r]) + (sv[8 + r] + sv[12 + r]);
#pragma unroll
      for (int xm = 1; xm < 16; xm <<= 1)
#pragma unroll
        for (int r = 0; r < 4; ++r) rs[r] += __shfl_xor(rs[r], xm, 64);
#pragma unroll
      for (int r = 0; r < 4; ++r) lsum[r] = lsum[r] * alpha[r] + rs[r];
#pragma unroll
      for (int t = 0; t < 8; ++t)
#pragma unroll
        for (int r = 0; r < 4; ++r) o[t][r] *= alpha[r];

      // stage P in per-wave swizzled LDS ([16][64], chunk ^= row&7)
#pragma unroll
      for (int jf = 0; jf < 4; ++jf)
#pragma unroll
        for (int r = 0; r < 4; ++r) {
          const int row = lg * 4 + r, col = jf * 16 + l15;
          Ps[w * 1024 + row * 64 + (((col >> 3) ^ (row & 7)) << 3) + (col & 7)] =
              (bf16_t)sv[jf * 4 + r];
        }
      asm volatile("s_waitcnt lgkmcnt(0)" ::: "memory");
      __builtin_amdgcn_sched_barrier(0);
    }

    // wait: V[jt] (issued this iter, before K[jn]) landed; K[jn]'s 3 stay in flight
    asm volatile("s_waitcnt vmcnt(3)" ::: "memory");
    __builtin_amdgcn_s_barrier();
    __builtin_amdgcn_sched_barrier(0);

    if (active) {
      bf16x8 pfr[2];
#pragma unroll
      for (int jk = 0; jk < 2; ++jk)
        pfr[jk] = *reinterpret_cast<const bf16x8*>(
            &Ps[w * 1024 + l15 * 64 + (((jk * 4 + lg) ^ (l15 & 7)) << 3)]);
      __builtin_amdgcn_s_setprio(1);
#pragma unroll
      for (int dt = 0; dt < 8; ++dt) {
        const int vrow = dt * 16 + l15;
        const int vsw = vrow & 7;
#pragma unroll
        for (int jk = 0; jk < 2; ++jk) {
          const int vc = (jk * 4 + lg) ^ vsw;
          bf16x8 vfr = *reinterpret_cast<const bf16x8*>(&Vs[vrow * 64 + vc * 8]);
          o[dt] = __builtin_amdgcn_mfma_f32_16x16x32_bf16(pfr[jk], vfr, o[dt], 0, 0, 0);
        }
      }
      __builtin_amdgcn_s_setprio(0);
    }
  }

  float inv[4];
#pragma unroll
  for (int r = 0; r < 4; ++r) inv[r] = 1.0f / lsum[r];
  const int b = bh >> 4, h = bh & 15;
#pragma unroll
  for (int dt = 0; dt < 8; ++dt)
#pragma unroll
    for (int r = 0; r < 4; ++r) {
      const int s = q0 + lg * 4 + r;
      att[((size_t)b * S_LEN + s) * 2048 + h * 128 + dt * 16 + l15] =
          (bf16_t)(o[dt][r] * inv[r]);
    }
}

// ---------------- host launch ----------------
extern "C" void kernel_launch(void* const* d_in, const int* in_sizes, int n_in,
                              void* d_out, int out_size, void* d_ws, size_t ws_size,
                              hipStream_t stream) {
  const float* x    = (const float*)d_in[0];
  const float* fcos = (const float*)d_in[1];
  const float* fsin = (const float*)d_in[2];
  const float* Wkv  = (const float*)d_in[3];
  const float* Wlq  = (const float*)d_in[4];
  const float* Wq   = (const float*)d_in[5];
  const float* Wk   = (const float*)d_in[6];
  const float* Wv   = (const float*)d_in[7];
  const float* Wqr  = (const float*)d_in[8];
  const float* bqr  = (const float*)d_in[9];
  const float* Wkr  = (const float*)d_in[10];
  const float* bkr  = (const float*)d_in[11];
  const float* Wo   = (const float*)d_in[12];
  const float* bo   = (const float*)d_in[13];
  float* out = (float*)d_out;

  char* ws = (char*)d_ws;
  size_t off = 0;
  auto alloc = [&](size_t bytes) {
    void* p = ws + off;
    off += (bytes + 255) & ~(size_t)255;
    return p;
  };
  bf16_t* xb    = (bf16_t*)alloc((size_t)MROWS * 2048 * 2);
  bf16_t* WcatA = (bf16_t*)alloc((size_t)3072 * 2048 * 2);  // [Wlq|Wkv|Wkr]^T, K=2048
  bf16_t* WcatB = (bf16_t*)alloc((size_t)3072 * 1536 * 2);  // [Wq|Wqr]^T,     K=1536
  bf16_t* WcatC = (bf16_t*)alloc((size_t)4096 * 512 * 2);   // [Wk|Wv]^T,      K=512
  bf16_t* WoT   = (bf16_t*)alloc((size_t)2048 * 2048 * 2);
  bf16_t* cq    = (bf16_t*)alloc((size_t)MROWS * 1536 * 2);
  bf16_t* ckv   = (bf16_t*)alloc((size_t)MROWS * 512 * 2);
  bf16_t* qfb   = (bf16_t*)alloc((size_t)NB * NH * S_LEN * DF * 2);
  bf16_t* kfb   = (bf16_t*)alloc((size_t)NB * NH * S_LEN * DF * 2);
  bf16_t* vTb   = (bf16_t*)alloc((size_t)NB * NH * HDIM * S_LEN * 2);
  bf16_t* attb  = (bf16_t*)alloc((size_t)MROWS * 2048 * 2);

  // 1. convert x
  {
    int n4 = (MROWS * 2048) / 4;
    convert_bf16<<<dim3((n4 + 255) / 256), dim3(256), 0, stream>>>(x, xb, n4);
  }
  // 2. transpose weights into concatenated (N,K) bf16 buffers
  auto tr = [&](const float* in, bf16_t* o_, int K, int N) {
    transpose_bf16<<<dim3(N / 64, K / 64), dim3(256), 0, stream>>>(in, o_, K, N);
  };
  tr(Wlq, WcatA, 2048, 1536);
  tr(Wkv, WcatA + (size_t)1536 * 2048, 2048, 512);
  tr(Wkr, WcatA + (size_t)2048 * 2048, 2048, 1024);
  tr(Wq,  WcatB, 1536, 2048);
  tr(Wqr, WcatB + (size_t)2048 * 1536, 1536, 1024);
  tr(Wk,  WcatC, 512, 2048);
  tr(Wv,  WcatC + (size_t)2048 * 512, 512, 2048);
  tr(Wo,  WoT, 2048, 2048);

  EpiParams ep{};

  // 3. fused: [cq | ckv | kr-rope->kf] = xb @ WcatA^T   (N=3072, K=2048)
  ep = {cq, ckv, kfb, nullptr, bkr, fcos, fsin};
  gemm_bt<5><<<dim3(3072 / 128, MROWS / 128), dim3(256), 0, stream>>>(
      xb, WcatA, MROWS, 3072, 2048, ep);
  // 4. fused: [q->qf | qr-rope->qf] = cq @ WcatB^T      (N=3072, K=1536)
  ep = {qfb, nullptr, nullptr, nullptr, bqr, fcos, fsin};
  gemm_bt<6><<<dim3(3072 / 128, MROWS / 128), dim3(256), 0, stream>>>(
      cq, WcatB, MROWS, 3072, 1536, ep);
  // 5. fused: [k->kf | v->vT] = ckv @ WcatC^T           (N=4096, K=512)
  ep = {kfb, vTb, nullptr, nullptr, nullptr, nullptr, nullptr};
  gemm_bt<7><<<dim3(4096 / 128, MROWS / 128), dim3(256), 0, stream>>>(
      ckv, WcatC, MROWS, 4096, 512, ep);
  // 6. attention: 1D grid, XCD-grouped swizzle inside the kernel
  attn_fwd<<<dim3(512), dim3(512), 0, stream>>>(qfb, kfb, vTb, attb);
  // 7. out = att @ Wo + bo  (f32)
  ep = {nullptr, nullptr, nullptr, out, bo, nullptr, nullptr};
  gemm_bt<1><<<dim3(2048 / 128, MROWS / 128), dim3(256), 0, stream>>>(
      attb, WoT, MROWS, 2048, 2048, ep);
}